// Round 10
// baseline (7069.789 us; speedup 1.0000x reference)
//
#include <hip/hip_runtime.h>
#include <hip/hip_fp16.h>

#define N 8192
#define ITERS 50
#define ROWS 8     // rows per gemv block (fallback path)
#define RPB 16     // rows per block (persistent path)
#define NBLK 512   // 256 CU x 2 blocks/CU, co-resident via launch_bounds(256,2)

typedef unsigned int uint32;

__device__ __forceinline__ uint32 pack2h(float x, float y) {
    __half2 p = __float22half2_rn(make_float2(x, y));
    return *reinterpret_cast<uint32*>(&p);
}

__device__ __forceinline__ float2 h2f(uint32 u) {
    __half2 h = *reinterpret_cast<__half2*>(&u);
    return __half22float2(h);
}

// software grid barrier: one counter slot per instance (zeroed per call).
__device__ __forceinline__ void gbar(int* cnt, int slot) {
    __syncthreads();
    __threadfence();
    if (threadIdx.x == 0) {
        __hip_atomic_fetch_add(&cnt[slot], 1, __ATOMIC_ACQ_REL,
                               __HIP_MEMORY_SCOPE_AGENT);
        while (__hip_atomic_load(&cnt[slot], __ATOMIC_ACQUIRE,
                                 __HIP_MEMORY_SCOPE_AGENT) < NBLK)
            __builtin_amdgcn_s_sleep(4);
    }
    __syncthreads();
    __threadfence();
}

// split epilogue: waves 0-1 hold rows 0-7 partials, waves 2-3 rows 8-15.
__device__ __forceinline__ void epi_split(float (&acc)[8], int t, int row0,
                                          float s, float* __restrict__ vout,
                                          float* __restrict__ nsq_next) {
#pragma unroll
    for (int r = 0; r < 8; ++r) {
        float a = acc[r];
        for (int off = 32; off > 0; off >>= 1) a += __shfl_down(a, off, 64);
        acc[r] = a;
    }
    __shared__ float part[4][8];
    const int wave = t >> 6, lane = t & 63;
    if (lane == 0) {
#pragma unroll
        for (int r = 0; r < 8; ++r) part[wave][r] = acc[r];
    }
    __syncthreads();
    float sq = 0.0f;
    if (t < RPB) {
        const float sum = (t < 8) ? part[0][t] + part[1][t]
                                  : part[2][t - 8] + part[3][t - 8];
        const float y = sum * s;
        vout[row0 + t] = y;
        sq = y * y;
    }
    if (wave == 0) {
        for (int off = 32; off > 0; off >>= 1) sq += __shfl_down(sq, off, 64);
        if (lane == 0) atomicAdd(nsq_next, sq);
    }
    __syncthreads();   // part[] reused next iteration
}

// zero barrier counters + nsq (fresh every call -> no cross-call state)
__global__ void pi_init2_kernel(int* __restrict__ cnt, float* __restrict__ nsq) {
    const int t = threadIdx.x;
    if (t < 64) cnt[t] = 0;
    if (t <= ITERS) nsq[t] = 0.0f;
}

// =========================== persistent kernel ==============================
// 512 blocks x 256 threads, 16 rows/block, row-split body: thread t owns
// 8 rows (rbase = row0 + (t>>7)*8) x uint4 column (t&127). 8 uint4 loads in
// flight per chunk per thread (r5's proven register budget).
__global__ __launch_bounds__(256, 2) void pi_persist_kernel(
        const float4* __restrict__ M4,
        __half* __restrict__ plane,
        float* __restrict__ vA,
        float* __restrict__ vB,
        float* __restrict__ nsq,
        int* __restrict__ cnt,
        float* __restrict__ out) {
    const int t = threadIdx.x;
    const int col = t & 127;
    const int row0 = blockIdx.x * RPB;
    const int rbase = row0 + (t >> 7) * 8;

    // ---- iter 1: v1 = M @ ones (fp32), convert to fp16 plane ----
    {
        uint2* hp2 = (uint2*)plane;            // row stride 2048 uint2
        float acc[8];
#pragma unroll
        for (int r = 0; r < 8; ++r) acc[r] = 0.0f;
        for (int c = 0; c < 16; ++c) {         // 16 chunks x 128 float4
            const int ci = c * 128 + col;
#pragma unroll
            for (int r = 0; r < 8; ++r) {
                const size_t off = (size_t)(rbase + r) * 2048 + ci;
                const float4 m = M4[off];
                acc[r] += m.x + m.y + m.z + m.w;
                uint2 o;
                o.x = pack2h(m.x, m.y);
                o.y = pack2h(m.z, m.w);
                hp2[off] = o;
            }
        }
        epi_split(acc, t, row0, 1.0f, vB, nsq + 1);
    }
    gbar(cnt, 1);

    // ---- iters 2..50: fp16 gemv ----
    const uint4* h4 = (const uint4*)plane;     // row stride 1024 uint4
    for (int k = 2; k <= ITERS; ++k) {
        const float* vin = (k & 1) ? vA : vB;
        float* vout      = (k & 1) ? vB : vA;
        const float s = rsqrtf(nsq[k - 1]);
        const float4* vin4 = (const float4*)vin;

        float acc[8];
#pragma unroll
        for (int r = 0; r < 8; ++r) acc[r] = 0.0f;
        for (int c = 0; c < 8; ++c) {          // 8 chunks x 128 uint4/row
            const int ci = c * 128 + col;
            const float4 va = vin4[2 * ci];
            const float4 vb = vin4[2 * ci + 1];
#pragma unroll
            for (int r = 0; r < 8; ++r) {
                const uint4 h = h4[(size_t)(rbase + r) * 1024 + ci];
                const float2 f0 = h2f(h.x);
                const float2 f1 = h2f(h.y);
                const float2 f2 = h2f(h.z);
                const float2 f3 = h2f(h.w);
                acc[r] += f0.x * va.x + f0.y * va.y + f1.x * va.z +
                          f1.y * va.w + f2.x * vb.x + f2.y * vb.y +
                          f3.x * vb.z + f3.y * vb.w;
            }
        }
        epi_split(acc, t, row0, s, vout, nsq + k);
        gbar(cnt, k);
    }

    // ---- final: out = v50 / ||v50|| (v50 unnormalized in vA) ----
    const float s = rsqrtf(nsq[ITERS]);
    if (t < RPB) out[row0 + t] = vA[row0 + t] * s;
}

// ============================ fallback (fp32) ================================
__global__ void pi_init_kernel(float* __restrict__ bufA, float* __restrict__ nsq) {
    int i = blockIdx.x * blockDim.x + threadIdx.x;
    if (i < N) bufA[i] = 1.0f;
    if (i <= ITERS) nsq[i] = (i == 0) ? 1.0f : 0.0f;
}

__device__ __forceinline__ void pi_epilogue8(float (&acc)[ROWS], int t, int row0,
                                             float s, float* __restrict__ vout,
                                             float* __restrict__ nsq_next) {
#pragma unroll
    for (int r = 0; r < ROWS; ++r) {
        float a = acc[r];
        for (int off = 32; off > 0; off >>= 1) a += __shfl_down(a, off, 64);
        acc[r] = a;
    }
    __shared__ float part[4][ROWS];
    const int wave = t >> 6, lane = t & 63;
    if (lane == 0) {
#pragma unroll
        for (int r = 0; r < ROWS; ++r) part[wave][r] = acc[r];
    }
    __syncthreads();
    float sq = 0.0f;
    if (t < ROWS) {
        const float sum = part[0][t] + part[1][t] + part[2][t] + part[3][t];
        const float y = sum * s;
        vout[row0 + t] = y;
        sq = y * y;
    }
    if (wave == 0) {
        for (int off = 32; off > 0; off >>= 1) sq += __shfl_down(sq, off, 64);
        if (lane == 0) atomicAdd(nsq_next, sq);
    }
}

__global__ __launch_bounds__(256) void pi_gemv_kernel(
        const float4* __restrict__ M4,
        const float4* __restrict__ vin4,
        float* __restrict__ vout,
        const float* __restrict__ nsq_prev,
        float* __restrict__ nsq_next) {
    const int t = threadIdx.x;
    const int row0 = blockIdx.x * ROWS;
    const float s = rsqrtf(*nsq_prev);
    float acc[ROWS];
#pragma unroll
    for (int r = 0; r < ROWS; ++r) acc[r] = 0.0f;
    for (int c = 0; c < 8; ++c) {
        const int idx = c * 256 + t;
        const float4 vv = vin4[idx];
#pragma unroll
        for (int r = 0; r < ROWS; ++r) {
            const float4 m = M4[(size_t)(row0 + r) * 2048 + idx];
            acc[r] += m.x * vv.x + m.y * vv.y + m.z * vv.z + m.w * vv.w;
        }
    }
    pi_epilogue8(acc, t, row0, s, vout, nsq_next);
}

__global__ void pi_scale_kernel(const float* __restrict__ vin,
                                const float* __restrict__ nsq,
                                float* __restrict__ out) {
    int i = blockIdx.x * blockDim.x + threadIdx.x;
    const float s = rsqrtf(*nsq);
    if (i < N) out[i] = vin[i] * s;
}

// ================================= launch ====================================
extern "C" void kernel_launch(void* const* d_in, const int* in_sizes, int n_in,
                              void* d_out, int out_size, void* d_ws, size_t ws_size,
                              hipStream_t stream) {
    const float* M = (const float*)d_in[0];
    float* out = (float*)d_out;

    const size_t H_BYTES = (size_t)N * N * 2;   // 128 MiB fp16 plane
    const size_t VEC_BYTES = (size_t)(2 * N + ITERS + 1 + 64) * sizeof(float);
    const bool use2 = (ws_size >= H_BYTES + VEC_BYTES);

    char* ws = (char*)d_ws;
    const float4* M4 = (const float4*)M;

    if (use2) {
        __half* plane = (__half*)ws;
        float* bufA = (float*)(ws + H_BYTES);
        float* bufB = bufA + N;
        float* nsq  = bufB + N;                 // ITERS+1 floats
        int*   cnt  = (int*)(nsq + ITERS + 1);  // 64 ints

        pi_init2_kernel<<<1, 256, 0, stream>>>(cnt, nsq);
        pi_persist_kernel<<<NBLK, 256, 0, stream>>>(
            M4, plane, bufA, bufB, nsq, cnt, out);
        return;
    }

    // fallback: fp32 multi-kernel path
    float* bufA = (float*)ws;
    float* bufB = bufA + N;
    float* nsq  = bufB + N;
    pi_init_kernel<<<(N + 255) / 256, 256, 0, stream>>>(bufA, nsq);
    for (int k = 1; k <= ITERS; ++k) {
        const float* vin = (k & 1) ? bufA : bufB;
        float* vout      = (k & 1) ? bufB : bufA;
        pi_gemv_kernel<<<N / ROWS, 256, 0, stream>>>(
            M4, (const float4*)vin, vout, nsq + (k - 1), nsq + k);
    }
    pi_scale_kernel<<<(N + 255) / 256, 256, 0, stream>>>(bufA, nsq + ITERS, out);
}

// Round 11
// 3688.065 us; speedup vs baseline: 1.9169x; 1.9169x over previous
//
#include <hip/hip_runtime.h>
#include <hip/hip_fp16.h>

#define N 8192
#define ITERS 50
#define ROWS 8     // rows per gemv block (fallback path)
#define RPB 16     // rows per block (persistent path)
#define NBLK 512   // 256 CU x 2 blocks/CU, co-resident via launch_bounds(256,2)
#define SLOT 32    // ints per barrier slot (128 B -> one cache line each)

typedef unsigned int uint32;
typedef unsigned long long uint64;

__device__ __forceinline__ uint32 pack2h(float x, float y) {
    __half2 p = __float22half2_rn(make_float2(x, y));
    return *reinterpret_cast<uint32*>(&p);
}

__device__ __forceinline__ float2 h2f(uint32 u) {
    __half2 h = *reinterpret_cast<__half2*>(&u);
    return __half22float2(h);
}

// agent-scope (cross-XCD coherent) accessors: bypass L1/L2, no fences needed
__device__ __forceinline__ float ldf_agent(const float* p) {
    return __hip_atomic_load(p, __ATOMIC_RELAXED, __HIP_MEMORY_SCOPE_AGENT);
}
__device__ __forceinline__ uint64 ld64_agent(const void* p) {
    return __hip_atomic_load((const uint64*)p, __ATOMIC_RELAXED,
                             __HIP_MEMORY_SCOPE_AGENT);
}
__device__ __forceinline__ void stf_agent(float* p, float v) {
    __hip_atomic_store(p, v, __ATOMIC_RELAXED, __HIP_MEMORY_SCOPE_AGENT);
}

// fence-free grid barrier: release-add + relaxed poll on a private cache line.
// __syncthreads drains vmcnt (stores retired) before the add; consumers read
// strictly after the closing __syncthreads, via agent-scope loads only.
__device__ __forceinline__ void gbar(int* cnt, int slot) {
    __syncthreads();
    if (threadIdx.x == 0) {
        __hip_atomic_fetch_add(&cnt[slot * SLOT], 1, __ATOMIC_RELEASE,
                               __HIP_MEMORY_SCOPE_AGENT);
        while (__hip_atomic_load(&cnt[slot * SLOT], __ATOMIC_RELAXED,
                                 __HIP_MEMORY_SCOPE_AGENT) < NBLK)
            __builtin_amdgcn_s_sleep(15);
    }
    __syncthreads();
}

// split epilogue: waves 0-1 hold rows 0-7 partials, waves 2-3 rows 8-15.
// vout written with agent-scope stores (cross-block visible without fences).
__device__ __forceinline__ void epi_split(float (&acc)[8], int t, int row0,
                                          float s, float* __restrict__ vout,
                                          float* __restrict__ nsq_next) {
#pragma unroll
    for (int r = 0; r < 8; ++r) {
        float a = acc[r];
        for (int off = 32; off > 0; off >>= 1) a += __shfl_down(a, off, 64);
        acc[r] = a;
    }
    __shared__ float part[4][8];
    const int wave = t >> 6, lane = t & 63;
    if (lane == 0) {
#pragma unroll
        for (int r = 0; r < 8; ++r) part[wave][r] = acc[r];
    }
    __syncthreads();
    float sq = 0.0f;
    if (t < RPB) {
        const float sum = (t < 8) ? part[0][t] + part[1][t]
                                  : part[2][t - 8] + part[3][t - 8];
        const float y = sum * s;
        stf_agent(&vout[row0 + t], y);
        sq = y * y;
    }
    if (wave == 0) {
        for (int off = 32; off > 0; off >>= 1) sq += __shfl_down(sq, off, 64);
        if (lane == 0) atomicAdd(nsq_next, sq);
    }
    __syncthreads();   // part[] reused next iteration
}

// zero barrier slots + nsq (fresh every call -> no cross-call state)
__global__ void pi_init2_kernel(int* __restrict__ cnt, float* __restrict__ nsq) {
    const int t = threadIdx.x;
    for (int i = t; i < (ITERS + 1) * SLOT; i += 256) cnt[i] = 0;
    if (t <= ITERS) nsq[t] = 0.0f;
}

// =========================== persistent kernel ==============================
// 512 blocks x 256 threads, 16 rows/block. Plane slab is BLOCK-PRIVATE
// (write iter1, read iters 2..50) -> normal loads, L2 stays warm. Only
// vout/nsq/cnt cross blocks -> agent-scope atomics. No __threadfence anywhere.
__global__ __launch_bounds__(256, 2) void pi_persist_kernel(
        const float4* __restrict__ M4,
        __half* __restrict__ plane,
        float* __restrict__ vA,
        float* __restrict__ vB,
        float* __restrict__ nsq,
        int* __restrict__ cnt,
        float* __restrict__ out) {
    const int t = threadIdx.x;
    const int col = t & 127;
    const int row0 = blockIdx.x * RPB;
    const int rbase = row0 + (t >> 7) * 8;

    // ---- iter 1: v1 = M @ ones (fp32), convert to fp16 plane (private) ----
    {
        uint2* hp2 = (uint2*)plane;            // row stride 2048 uint2
        float acc[8];
#pragma unroll
        for (int r = 0; r < 8; ++r) acc[r] = 0.0f;
        for (int c = 0; c < 16; ++c) {         // 16 chunks x 128 float4
            const int ci = c * 128 + col;
#pragma unroll
            for (int r = 0; r < 8; ++r) {
                const size_t off = (size_t)(rbase + r) * 2048 + ci;
                const float4 m = M4[off];
                acc[r] += m.x + m.y + m.z + m.w;
                uint2 o;
                o.x = pack2h(m.x, m.y);
                o.y = pack2h(m.z, m.w);
                hp2[off] = o;
            }
        }
        epi_split(acc, t, row0, 1.0f, vB, nsq + 1);
    }
    gbar(cnt, 1);

    // ---- iters 2..50: fp16 gemv; vin/nsq via agent loads ----
    const uint4* h4 = (const uint4*)plane;     // row stride 1024 uint4
    for (int k = 2; k <= ITERS; ++k) {
        const float* vin = (k & 1) ? vA : vB;
        float* vout      = (k & 1) ? vB : vA;
        const float s = rsqrtf(ldf_agent(&nsq[k - 1]));

        float acc[8];
#pragma unroll
        for (int r = 0; r < 8; ++r) acc[r] = 0.0f;
        for (int c = 0; c < 8; ++c) {          // 8 chunks x 128 uint4/row
            const int ci = c * 128 + col;
            const float* vp = vin + 8 * ci;    // elems 8ci..8ci+7
            const uint64 w0 = ld64_agent(vp + 0);
            const uint64 w1 = ld64_agent(vp + 2);
            const uint64 w2 = ld64_agent(vp + 4);
            const uint64 w3 = ld64_agent(vp + 6);
            const float vax = __uint_as_float((uint32)w0);
            const float vay = __uint_as_float((uint32)(w0 >> 32));
            const float vaz = __uint_as_float((uint32)w1);
            const float vaw = __uint_as_float((uint32)(w1 >> 32));
            const float vbx = __uint_as_float((uint32)w2);
            const float vby = __uint_as_float((uint32)(w2 >> 32));
            const float vbz = __uint_as_float((uint32)w3);
            const float vbw = __uint_as_float((uint32)(w3 >> 32));
#pragma unroll
            for (int r = 0; r < 8; ++r) {
                const uint4 h = h4[(size_t)(rbase + r) * 1024 + ci];
                const float2 f0 = h2f(h.x);
                const float2 f1 = h2f(h.y);
                const float2 f2 = h2f(h.z);
                const float2 f3 = h2f(h.w);
                acc[r] += f0.x * vax + f0.y * vay + f1.x * vaz +
                          f1.y * vaw + f2.x * vbx + f2.y * vby +
                          f3.x * vbz + f3.y * vbw;
            }
        }
        epi_split(acc, t, row0, s, vout, nsq + k);
        gbar(cnt, k);
    }

    // ---- final: out = v50 / ||v50|| (v50 unnormalized in vA) ----
    const float s = rsqrtf(ldf_agent(&nsq[ITERS]));
    if (t < RPB) out[row0 + t] = ldf_agent(&vA[row0 + t]) * s;
}

// ============================ fallback (fp32) ================================
__global__ void pi_init_kernel(float* __restrict__ bufA, float* __restrict__ nsq) {
    int i = blockIdx.x * blockDim.x + threadIdx.x;
    if (i < N) bufA[i] = 1.0f;
    if (i <= ITERS) nsq[i] = (i == 0) ? 1.0f : 0.0f;
}

__device__ __forceinline__ void pi_epilogue8(float (&acc)[ROWS], int t, int row0,
                                             float s, float* __restrict__ vout,
                                             float* __restrict__ nsq_next) {
#pragma unroll
    for (int r = 0; r < ROWS; ++r) {
        float a = acc[r];
        for (int off = 32; off > 0; off >>= 1) a += __shfl_down(a, off, 64);
        acc[r] = a;
    }
    __shared__ float part[4][ROWS];
    const int wave = t >> 6, lane = t & 63;
    if (lane == 0) {
#pragma unroll
        for (int r = 0; r < ROWS; ++r) part[wave][r] = acc[r];
    }
    __syncthreads();
    float sq = 0.0f;
    if (t < ROWS) {
        const float sum = part[0][t] + part[1][t] + part[2][t] + part[3][t];
        const float y = sum * s;
        vout[row0 + t] = y;
        sq = y * y;
    }
    if (wave == 0) {
        for (int off = 32; off > 0; off >>= 1) sq += __shfl_down(sq, off, 64);
        if (lane == 0) atomicAdd(nsq_next, sq);
    }
}

__global__ __launch_bounds__(256) void pi_gemv_kernel(
        const float4* __restrict__ M4,
        const float4* __restrict__ vin4,
        float* __restrict__ vout,
        const float* __restrict__ nsq_prev,
        float* __restrict__ nsq_next) {
    const int t = threadIdx.x;
    const int row0 = blockIdx.x * ROWS;
    const float s = rsqrtf(*nsq_prev);
    float acc[ROWS];
#pragma unroll
    for (int r = 0; r < ROWS; ++r) acc[r] = 0.0f;
    for (int c = 0; c < 8; ++c) {
        const int idx = c * 256 + t;
        const float4 vv = vin4[idx];
#pragma unroll
        for (int r = 0; r < ROWS; ++r) {
            const float4 m = M4[(size_t)(row0 + r) * 2048 + idx];
            acc[r] += m.x * vv.x + m.y * vv.y + m.z * vv.z + m.w * vv.w;
        }
    }
    pi_epilogue8(acc, t, row0, s, vout, nsq_next);
}

__global__ void pi_scale_kernel(const float* __restrict__ vin,
                                const float* __restrict__ nsq,
                                float* __restrict__ out) {
    int i = blockIdx.x * blockDim.x + threadIdx.x;
    const float s = rsqrtf(*nsq);
    if (i < N) out[i] = vin[i] * s;
}

// ================================= launch ====================================
extern "C" void kernel_launch(void* const* d_in, const int* in_sizes, int n_in,
                              void* d_out, int out_size, void* d_ws, size_t ws_size,
                              hipStream_t stream) {
    const float* M = (const float*)d_in[0];
    float* out = (float*)d_out;

    const size_t H_BYTES = (size_t)N * N * 2;   // 128 MiB fp16 plane
    const size_t VEC_BYTES =
        (size_t)(2 * N + 64 + (ITERS + 1) * SLOT + 1024) * sizeof(float);
    const bool use2 = (ws_size >= H_BYTES + VEC_BYTES);

    char* ws = (char*)d_ws;
    const float4* M4 = (const float4*)M;

    if (use2) {
        __half* plane = (__half*)ws;
        float* bufA = (float*)(ws + H_BYTES);
        float* bufB = bufA + N;
        float* nsq  = bufB + N;                 // ITERS+1 floats
        int*   cnt  = (int*)(nsq + 64);         // 128B-aligned, 51 slots x 32 ints

        pi_init2_kernel<<<1, 256, 0, stream>>>(cnt, nsq);
        pi_persist_kernel<<<NBLK, 256, 0, stream>>>(
            M4, plane, bufA, bufB, nsq, cnt, out);
        return;
    }

    // fallback: fp32 multi-kernel path
    float* bufA = (float*)ws;
    float* bufB = bufA + N;
    float* nsq  = bufB + N;
    pi_init_kernel<<<(N + 255) / 256, 256, 0, stream>>>(bufA, nsq);
    for (int k = 1; k <= ITERS; ++k) {
        const float* vin = (k & 1) ? bufA : bufB;
        float* vout      = (k & 1) ? bufB : bufA;
        pi_gemv_kernel<<<N / ROWS, 256, 0, stream>>>(
            M4, (const float4*)vin, vout, nsq + (k - 1), nsq + k);
    }
    pi_scale_kernel<<<(N + 255) / 256, 256, 0, stream>>>(bufA, nsq + ITERS, out);
}

// Round 12
// 3075.342 us; speedup vs baseline: 2.2989x; 1.1992x over previous
//
#include <hip/hip_runtime.h>
#include <hip/hip_fp16.h>

#define N 8192
#define ITERS 50
#define ROWS 8     // rows per gemv block (fallback path)
#define RPB 16     // rows per block (persistent path)
#define NBLK 512   // 256 CU x 2 blocks/CU, co-resident via launch_bounds(256,2)
#define SLOT 32    // ints per barrier slot (128 B -> one cache line each)

typedef unsigned int uint32;
typedef unsigned long long uint64;

__device__ __forceinline__ uint32 pack2h(float x, float y) {
    __half2 p = __float22half2_rn(make_float2(x, y));
    return *reinterpret_cast<uint32*>(&p);
}

__device__ __forceinline__ float2 h2f(uint32 u) {
    __half2 h = *reinterpret_cast<__half2*>(&u);
    return __half22float2(h);
}

// agent-scope (cross-XCD coherent) accessors: served at the coherence point,
// no cache-maintenance instructions needed
__device__ __forceinline__ float ldf_agent(const float* p) {
    return __hip_atomic_load(p, __ATOMIC_RELAXED, __HIP_MEMORY_SCOPE_AGENT);
}
__device__ __forceinline__ uint64 ld64_agent(const void* p) {
    return __hip_atomic_load((const uint64*)p, __ATOMIC_RELAXED,
                             __HIP_MEMORY_SCOPE_AGENT);
}
__device__ __forceinline__ void stf_agent(float* p, float v) {
    __hip_atomic_store(p, v, __ATOMIC_RELAXED, __HIP_MEMORY_SCOPE_AGENT);
}

// grid barrier, fully relaxed: all cross-block data (vout/nsq) is written at
// the coherence point BEFORE __syncthreads (whose s_waitcnt vmcnt(0) retires
// those writes), so a RELAXED add is sufficient — a RELEASE add would emit a
// per-block L2 writeback (buffer_wbl2), which serialized at ~64/XCD/iter and
// dominated rounds 9-11.
__device__ __forceinline__ void gbar(int* cnt, int slot) {
    __syncthreads();
    if (threadIdx.x == 0) {
        __hip_atomic_fetch_add(&cnt[slot * SLOT], 1, __ATOMIC_RELAXED,
                               __HIP_MEMORY_SCOPE_AGENT);
        while (__hip_atomic_load(&cnt[slot * SLOT], __ATOMIC_RELAXED,
                                 __HIP_MEMORY_SCOPE_AGENT) < NBLK)
            __builtin_amdgcn_s_sleep(15);
    }
    __syncthreads();
}

// split epilogue: waves 0-1 hold rows 0-7 partials, waves 2-3 rows 8-15.
// vout written with agent-scope stores (cross-block visible without fences).
__device__ __forceinline__ void epi_split(float (&acc)[8], int t, int row0,
                                          float s, float* __restrict__ vout,
                                          float* __restrict__ nsq_next) {
#pragma unroll
    for (int r = 0; r < 8; ++r) {
        float a = acc[r];
        for (int off = 32; off > 0; off >>= 1) a += __shfl_down(a, off, 64);
        acc[r] = a;
    }
    __shared__ float part[4][8];
    const int wave = t >> 6, lane = t & 63;
    if (lane == 0) {
#pragma unroll
        for (int r = 0; r < 8; ++r) part[wave][r] = acc[r];
    }
    __syncthreads();
    float sq = 0.0f;
    if (t < RPB) {
        const float sum = (t < 8) ? part[0][t] + part[1][t]
                                  : part[2][t - 8] + part[3][t - 8];
        const float y = sum * s;
        stf_agent(&vout[row0 + t], y);
        sq = y * y;
    }
    if (wave == 0) {
        for (int off = 32; off > 0; off >>= 1) sq += __shfl_down(sq, off, 64);
        if (lane == 0) atomicAdd(nsq_next, sq);
    }
    __syncthreads();   // part[] reused next iteration
}

// zero barrier slots + nsq (fresh every call -> no cross-call state)
__global__ void pi_init2_kernel(int* __restrict__ cnt, float* __restrict__ nsq) {
    const int t = threadIdx.x;
    for (int i = t; i < (ITERS + 1) * SLOT; i += 256) cnt[i] = 0;
    if (t <= ITERS) nsq[t] = 0.0f;
}

// =========================== persistent kernel ==============================
// 512 blocks x 256 threads, 16 rows/block. Plane slab is BLOCK-PRIVATE
// (write iter1, read iters 2..50) -> normal loads, L2 stays warm. Only
// vout/nsq/cnt cross blocks -> agent-scope atomics. No fences, no release.
__global__ __launch_bounds__(256, 2) void pi_persist_kernel(
        const float4* __restrict__ M4,
        __half* __restrict__ plane,
        float* __restrict__ vA,
        float* __restrict__ vB,
        float* __restrict__ nsq,
        int* __restrict__ cnt,
        float* __restrict__ out) {
    const int t = threadIdx.x;
    const int col = t & 127;
    const int row0 = blockIdx.x * RPB;
    const int rbase = row0 + (t >> 7) * 8;

    // ---- iter 1: v1 = M @ ones (fp32), convert to fp16 plane (private) ----
    {
        uint2* hp2 = (uint2*)plane;            // row stride 2048 uint2
        float acc[8];
#pragma unroll
        for (int r = 0; r < 8; ++r) acc[r] = 0.0f;
        for (int c = 0; c < 16; ++c) {         // 16 chunks x 128 float4
            const int ci = c * 128 + col;
#pragma unroll
            for (int r = 0; r < 8; ++r) {
                const size_t off = (size_t)(rbase + r) * 2048 + ci;
                const float4 m = M4[off];
                acc[r] += m.x + m.y + m.z + m.w;
                uint2 o;
                o.x = pack2h(m.x, m.y);
                o.y = pack2h(m.z, m.w);
                hp2[off] = o;
            }
        }
        epi_split(acc, t, row0, 1.0f, vB, nsq + 1);
    }
    gbar(cnt, 1);

    // ---- iters 2..50: fp16 gemv; vin/nsq via agent loads ----
    const uint4* h4 = (const uint4*)plane;     // row stride 1024 uint4
    for (int k = 2; k <= ITERS; ++k) {
        const float* vin = (k & 1) ? vA : vB;
        float* vout      = (k & 1) ? vB : vA;
        const float s = rsqrtf(ldf_agent(&nsq[k - 1]));

        float acc[8];
#pragma unroll
        for (int r = 0; r < 8; ++r) acc[r] = 0.0f;
        for (int c = 0; c < 8; ++c) {          // 8 chunks x 128 uint4/row
            const int ci = c * 128 + col;
            const float* vp = vin + 8 * ci;    // elems 8ci..8ci+7
            const uint64 w0 = ld64_agent(vp + 0);
            const uint64 w1 = ld64_agent(vp + 2);
            const uint64 w2 = ld64_agent(vp + 4);
            const uint64 w3 = ld64_agent(vp + 6);
            const float vax = __uint_as_float((uint32)w0);
            const float vay = __uint_as_float((uint32)(w0 >> 32));
            const float vaz = __uint_as_float((uint32)w1);
            const float vaw = __uint_as_float((uint32)(w1 >> 32));
            const float vbx = __uint_as_float((uint32)w2);
            const float vby = __uint_as_float((uint32)(w2 >> 32));
            const float vbz = __uint_as_float((uint32)w3);
            const float vbw = __uint_as_float((uint32)(w3 >> 32));
#pragma unroll
            for (int r = 0; r < 8; ++r) {
                const uint4 h = h4[(size_t)(rbase + r) * 1024 + ci];
                const float2 f0 = h2f(h.x);
                const float2 f1 = h2f(h.y);
                const float2 f2 = h2f(h.z);
                const float2 f3 = h2f(h.w);
                acc[r] += f0.x * vax + f0.y * vay + f1.x * vaz +
                          f1.y * vaw + f2.x * vbx + f2.y * vby +
                          f3.x * vbz + f3.y * vbw;
            }
        }
        epi_split(acc, t, row0, s, vout, nsq + k);
        gbar(cnt, k);
    }

    // ---- final: out = v50 / ||v50|| (v50 unnormalized in vA) ----
    const float s = rsqrtf(ldf_agent(&nsq[ITERS]));
    if (t < RPB) out[row0 + t] = ldf_agent(&vA[row0 + t]) * s;
}

// ============================ fallback (fp32) ================================
__global__ void pi_init_kernel(float* __restrict__ bufA, float* __restrict__ nsq) {
    int i = blockIdx.x * blockDim.x + threadIdx.x;
    if (i < N) bufA[i] = 1.0f;
    if (i <= ITERS) nsq[i] = (i == 0) ? 1.0f : 0.0f;
}

__device__ __forceinline__ void pi_epilogue8(float (&acc)[ROWS], int t, int row0,
                                             float s, float* __restrict__ vout,
                                             float* __restrict__ nsq_next) {
#pragma unroll
    for (int r = 0; r < ROWS; ++r) {
        float a = acc[r];
        for (int off = 32; off > 0; off >>= 1) a += __shfl_down(a, off, 64);
        acc[r] = a;
    }
    __shared__ float part[4][ROWS];
    const int wave = t >> 6, lane = t & 63;
    if (lane == 0) {
#pragma unroll
        for (int r = 0; r < ROWS; ++r) part[wave][r] = acc[r];
    }
    __syncthreads();
    float sq = 0.0f;
    if (t < ROWS) {
        const float sum = part[0][t] + part[1][t] + part[2][t] + part[3][t];
        const float y = sum * s;
        vout[row0 + t] = y;
        sq = y * y;
    }
    if (wave == 0) {
        for (int off = 32; off > 0; off >>= 1) sq += __shfl_down(sq, off, 64);
        if (lane == 0) atomicAdd(nsq_next, sq);
    }
}

__global__ __launch_bounds__(256) void pi_gemv_kernel(
        const float4* __restrict__ M4,
        const float4* __restrict__ vin4,
        float* __restrict__ vout,
        const float* __restrict__ nsq_prev,
        float* __restrict__ nsq_next) {
    const int t = threadIdx.x;
    const int row0 = blockIdx.x * ROWS;
    const float s = rsqrtf(*nsq_prev);
    float acc[ROWS];
#pragma unroll
    for (int r = 0; r < ROWS; ++r) acc[r] = 0.0f;
    for (int c = 0; c < 8; ++c) {
        const int idx = c * 256 + t;
        const float4 vv = vin4[idx];
#pragma unroll
        for (int r = 0; r < ROWS; ++r) {
            const float4 m = M4[(size_t)(row0 + r) * 2048 + idx];
            acc[r] += m.x * vv.x + m.y * vv.y + m.z * vv.z + m.w * vv.w;
        }
    }
    pi_epilogue8(acc, t, row0, s, vout, nsq_next);
}

__global__ void pi_scale_kernel(const float* __restrict__ vin,
                                const float* __restrict__ nsq,
                                float* __restrict__ out) {
    int i = blockIdx.x * blockDim.x + threadIdx.x;
    const float s = rsqrtf(*nsq);
    if (i < N) out[i] = vin[i] * s;
}

// ================================= launch ====================================
extern "C" void kernel_launch(void* const* d_in, const int* in_sizes, int n_in,
                              void* d_out, int out_size, void* d_ws, size_t ws_size,
                              hipStream_t stream) {
    const float* M = (const float*)d_in[0];
    float* out = (float*)d_out;

    const size_t H_BYTES = (size_t)N * N * 2;   // 128 MiB fp16 plane
    const size_t VEC_BYTES =
        (size_t)(2 * N + 64 + (ITERS + 1) * SLOT + 1024) * sizeof(float);
    const bool use2 = (ws_size >= H_BYTES + VEC_BYTES);

    char* ws = (char*)d_ws;
    const float4* M4 = (const float4*)M;

    if (use2) {
        __half* plane = (__half*)ws;
        float* bufA = (float*)(ws + H_BYTES);
        float* bufB = bufA + N;
        float* nsq  = bufB + N;                 // ITERS+1 floats
        int*   cnt  = (int*)(nsq + 64);         // 128B-aligned, 51 slots x 32 ints

        pi_init2_kernel<<<1, 256, 0, stream>>>(cnt, nsq);
        pi_persist_kernel<<<NBLK, 256, 0, stream>>>(
            M4, plane, bufA, bufB, nsq, cnt, out);
        return;
    }

    // fallback: fp32 multi-kernel path
    float* bufA = (float*)ws;
    float* bufB = bufA + N;
    float* nsq  = bufB + N;
    pi_init_kernel<<<(N + 255) / 256, 256, 0, stream>>>(bufA, nsq);
    for (int k = 1; k <= ITERS; ++k) {
        const float* vin = (k & 1) ? bufA : bufB;
        float* vout      = (k & 1) ? bufB : bufA;
        pi_gemv_kernel<<<N / ROWS, 256, 0, stream>>>(
            M4, (const float4*)vin, vout, nsq + (k - 1), nsq + k);
    }
    pi_scale_kernel<<<(N + 255) / 256, 256, 0, stream>>>(bufA, nsq + ITERS, out);
}